// Round 7
// baseline (468.074 us; speedup 1.0000x reference)
//
#include <hip/hip_runtime.h>
#include <hip/hip_bf16.h>

// SparseGroupConv2d: y = blockdiag(W) @ x, 8 groups of 128 channels.
// Per group g: Y_g[128, 65536] = W_diag[128,128] @ X_g[128, 65536]. Mask unread.
//
// v3: concurrency fix. v2 reached ~126us @ ~4.3 TB/s with only 2 blocks/CU
// (66 KB LDS, ~180 VGPR): HBM idles while both resident blocks do cvt/MFMA/
// store. v3 pre-converts W to bf16 MFMA-fragment-major layout in d_ws (one
// tiny 8-block kernel), so the main kernel loads A-fragments as coalesced
// dwordx4 from L2: no W LDS, no W cvt, no wr[] regs. LDS 33 KB + ~110 VGPR
// -> 4 blocks/CU, shorter per-block serial chain.

#define GC   128       // channels per group
#define CIN  1024      // W row stride
#define PT   65536     // pixels (H*W)
#define BN   128       // pixels per block
#define XLD  132       // X LDS row length (pad +4 keeps 8B align, breaks pow2 stride)
#define WFRAG_PER_G (4 * 8 * 64 * 8)   // 16384 bf16 elems per group

typedef __attribute__((ext_vector_type(8))) short bf16x8;  // 8 bf16 = 4 VGPR
typedef __attribute__((ext_vector_type(4))) float f32x4;   // MFMA 16x16 accum

__device__ __forceinline__ unsigned short f2bf(float f) {
    union { float f; unsigned int u; } v; v.f = f;
    unsigned int r = v.u + 0x7FFF + ((v.u >> 16) & 1);
    return (unsigned short)(r >> 16);
}

// ---- pre-kernel: W fp32 diag blocks -> bf16 fragment-major in d_ws ----
// frag id f = ks*8+mi, lane 0..63: elems W[mi*16+(lane&15)][ks*32+(lane>>4)*8+j]
// stored at wf[g*16384 + (f*64+lane)*8 + j]  (16 B per (f,lane), coalesced)
__global__ __launch_bounds__(256) void wprep_kernel(
        const float* __restrict__ w, unsigned short* __restrict__ wf) {
    const int g = blockIdx.x;
    const int t = threadIdx.x;
    #pragma unroll
    for (int i = 0; i < 8; ++i) {
        const int id   = i * 256 + t;     // (f,lane) pair index, 0..2047
        const int f    = id >> 6;
        const int lane = id & 63;
        const int mi = f & 7, ks = f >> 3;
        const int row = g * GC + mi * 16 + (lane & 15);
        const int col = g * GC + ks * 32 + (lane >> 4) * 8;
        const float4 w0 = *reinterpret_cast<const float4*>(w + (size_t)row * CIN + col);
        const float4 w1 = *reinterpret_cast<const float4*>(w + (size_t)row * CIN + col + 4);
        ushort4 h0, h1;
        h0.x = f2bf(w0.x); h0.y = f2bf(w0.y); h0.z = f2bf(w0.z); h0.w = f2bf(w0.w);
        h1.x = f2bf(w1.x); h1.y = f2bf(w1.y); h1.z = f2bf(w1.z); h1.w = f2bf(w1.w);
        unsigned short* dst = wf + (size_t)g * WFRAG_PER_G + (size_t)id * 8;
        *reinterpret_cast<ushort4*>(dst)     = h0;
        *reinterpret_cast<ushort4*>(dst + 4) = h1;
    }
}

__global__ __launch_bounds__(256, 4) void sparse_group_conv_kernel(
        const float* __restrict__ x, const unsigned short* __restrict__ wf,
        float* __restrict__ y) {
    __shared__ unsigned short Xlds[GC * XLD];  // 33 KB

    const int t  = threadIdx.x;
    const int g  = blockIdx.y;
    const int p0 = blockIdx.x * BN;

    const float* Xg = x + (size_t)(g * GC) * PT + p0;

    // ---- issue all 16 X loads (dwordx4), deep in-flight ----
    float4 xr[16];   // X tile [128 k][128 px] fp32: 4096 float4 / 256 thr
    #pragma unroll
    for (int it = 0; it < 16; ++it) {
        const int f_i = it * 256 + t;
        const int row = f_i >> 5;            // 32 float4 per row
        const int m   = f_i & 31;
        xr[it] = *reinterpret_cast<const float4*>(Xg + (size_t)row * PT + 4 * m);
    }
    // ---- cvt + LDS write ----
    #pragma unroll
    for (int it = 0; it < 16; ++it) {
        const int f_i = it * 256 + t;
        const int row = f_i >> 5;
        const int m   = f_i & 31;
        ushort4 h;
        h.x = f2bf(xr[it].x); h.y = f2bf(xr[it].y);
        h.z = f2bf(xr[it].z); h.w = f2bf(xr[it].w);
        *reinterpret_cast<ushort4*>(&Xlds[row * XLD + 4 * m]) = h;
    }
    __syncthreads();

    // ---- compute: wave wv owns px [wv*32, +32), all 128 output rows ----
    const int lane = t & 63;
    const int wv   = t >> 6;
    const int r    = lane & 15;   // frag row (A: m) / col (B,D: pixel)
    const int q    = lane >> 4;   // k sub-block (A,B) / row block (D)

    const unsigned short* wg = wf + (size_t)g * WFRAG_PER_G + (size_t)lane * 8;

    f32x4 acc[2][8];
    #pragma unroll
    for (int pg = 0; pg < 2; ++pg)
        #pragma unroll
        for (int mi = 0; mi < 8; ++mi)
            acc[pg][mi] = (f32x4){0.f, 0.f, 0.f, 0.f};

    #pragma unroll
    for (int ks = 0; ks < 4; ++ks) {          // K = 128 in 4 MFMA K-steps
        bf16x8 b[2];
        #pragma unroll
        for (int pg = 0; pg < 2; ++pg) {
            const int px = wv * 32 + pg * 16 + r;
            const unsigned short* col = &Xlds[(ks * 32 + q * 8) * XLD + px];
            short tmp[8];
            #pragma unroll
            for (int j = 0; j < 8; ++j) tmp[j] = (short)col[j * XLD];
            b[pg] = (bf16x8){tmp[0], tmp[1], tmp[2], tmp[3],
                             tmp[4], tmp[5], tmp[6], tmp[7]};
        }
        #pragma unroll
        for (int mi = 0; mi < 8; ++mi) {
            const bf16x8 a = *reinterpret_cast<const bf16x8*>(
                wg + (size_t)((ks * 8 + mi) * 64) * 8);
            acc[0][mi] = __builtin_amdgcn_mfma_f32_16x16x32_bf16(a, b[0], acc[0][mi], 0, 0, 0);
            acc[1][mi] = __builtin_amdgcn_mfma_f32_16x16x32_bf16(a, b[1], acc[1][mi], 0, 0, 0);
        }
    }

    // ---- stores ----
    float* Yg = y + (size_t)(g * GC) * PT + p0;
    #pragma unroll
    for (int pg = 0; pg < 2; ++pg) {
        float* yp = Yg + wv * 32 + pg * 16 + r;
        #pragma unroll
        for (int mi = 0; mi < 8; ++mi) {
            #pragma unroll
            for (int rr = 0; rr < 4; ++rr) {
                yp[(size_t)(mi * 16 + q * 4 + rr) * PT] = acc[pg][mi][rr];
            }
        }
    }
}

extern "C" void kernel_launch(void* const* d_in, const int* in_sizes, int n_in,
                              void* d_out, int out_size, void* d_ws, size_t ws_size,
                              hipStream_t stream) {
    const float* x = (const float*)d_in[0];   // [1, 1024, 256, 256] fp32
    const float* w = (const float*)d_in[1];   // [1024, 1024] fp32
    // d_in[2] = mask: known block-diagonal pattern, not needed.
    float* y = (float*)d_out;                 // [1, 1024, 256, 256] fp32
    unsigned short* wf = (unsigned short*)d_ws;  // 256 KB bf16 W fragments

    wprep_kernel<<<dim3(8), dim3(256), 0, stream>>>(w, wf);
    dim3 grid(PT / BN, 8);   // 512 pixel tiles x 8 groups = 4096 blocks
    sparse_group_conv_kernel<<<grid, dim3(256), 0, stream>>>(x, wf, y);
}

// Round 8
// 447.775 us; speedup vs baseline: 1.0453x; 1.0453x over previous
//
#include <hip/hip_runtime.h>
#include <hip/hip_bf16.h>

// SparseGroupConv2d: y = blockdiag(W) @ x, 8 groups of 128 channels.
// Per group g: Y_g[128, 65536] = W_diag[128,128] @ X_g[128, 65536]. Mask unread.
//
// v4: v2 core (LDS W swizzled + LDS X + ds-read fragments) minus its serial
// overheads. v3 showed A-frags-from-L2 in the inner loop regresses (vmcnt
// stalls); v2 showed 2 blocks/CU can't hide ~2k-cyc cvt/gather phases.
// v4: wprep pre-converts W -> bf16 PRE-SWIZZLED in d_ws (W cvt off the block
// path; staging = 8 L2 loads + 8 ds_write_b128); X cvt via __float2bfloat16;
// BN=64 -> LDS 49 KB -> 3 blocks/CU (12 waves).

#define GC   128       // channels per group
#define CIN  1024      // W row stride
#define PT   65536     // pixels (H*W)
#define BN   64        // pixels per block (4 waves x 16 px)
#define XLD  68        // X LDS row stride in u16 (pad +4: 8B-aligned ushort4 writes)
#define WG_ELEMS (GC * GC)   // 16384 bf16 per group (32 KB)

typedef __attribute__((ext_vector_type(8))) short bf16x8;  // 8 bf16 = 4 VGPR
typedef __attribute__((ext_vector_type(4))) float f32x4;   // MFMA 16x16 accum

__device__ __forceinline__ unsigned short f2bf(float f) {
    __hip_bfloat16 h = __float2bfloat16(f);   // compiler emits packed cvt
    return *reinterpret_cast<unsigned short*>(&h);
}

// ---- pre-kernel: W fp32 diag blocks -> bf16, PRE-SWIZZLED row-major ----
// wf[g*16384 + ((mm*128 + k) ^ ((mm&7)<<3)) .. +7] = bf16(W[g*128+mm][g*128+k..+7])
// XOR touches u16-idx bits 3..5 only; k ≡ 0 mod 8 keeps each 16 B block intact.
__global__ __launch_bounds__(256) void wprep_kernel(
        const float* __restrict__ w, unsigned short* __restrict__ wf) {
    const int b = blockIdx.x;            // 64 blocks: g = b>>3, s = b&7
    const int g = b >> 3, s = b & 7;
    const int t = threadIdx.x;
    const int mm = s * 16 + (t >> 4);    // output row within group
    const int k  = (t & 15) * 8;         // 8 consecutive k
    const float* src = w + (size_t)(g * GC + mm) * CIN + g * GC + k;
    const float4 w0 = *reinterpret_cast<const float4*>(src);
    const float4 w1 = *reinterpret_cast<const float4*>(src + 4);
    ushort4 h0, h1;
    h0.x = f2bf(w0.x); h0.y = f2bf(w0.y); h0.z = f2bf(w0.z); h0.w = f2bf(w0.w);
    h1.x = f2bf(w1.x); h1.y = f2bf(w1.y); h1.z = f2bf(w1.z); h1.w = f2bf(w1.w);
    const int idx = (mm * GC + k) ^ ((mm & 7) << 3);
    unsigned short* dst = wf + (size_t)g * WG_ELEMS + idx;
    *reinterpret_cast<ushort4*>(dst)     = h0;
    *reinterpret_cast<ushort4*>(dst + 4) = h1;
}

__global__ __launch_bounds__(256) void sparse_group_conv_kernel(
        const float* __restrict__ x, const unsigned short* __restrict__ wf,
        float* __restrict__ y) {
    __shared__ unsigned short Wlds[GC * GC];   // 32 KB, arrives pre-swizzled
    __shared__ unsigned short Xlds[GC * XLD];  // 17 KB

    const int t  = threadIdx.x;
    const int g  = blockIdx.y;
    const int p0 = blockIdx.x * BN;

    // ---- issue W loads first (L2-hot, FIFO-retire early), then X (HBM) ----
    const unsigned short* wsrc = wf + (size_t)g * WG_ELEMS + t * 8;
    uint4 wr[8];                       // 8 x 16 B = 32 KB / 256 thr
    #pragma unroll
    for (int it = 0; it < 8; ++it)
        wr[it] = *reinterpret_cast<const uint4*>(wsrc + it * 2048);

    const float* Xg = x + (size_t)(g * GC) * PT + p0;
    float4 xr[8];                      // X tile [128 k][64 px] fp32: 2048 float4
    #pragma unroll
    for (int it = 0; it < 8; ++it) {
        const int f_i = it * 256 + t;  // row = f_i>>4 (16 float4 per row)
        const int row = f_i >> 4, m = f_i & 15;
        xr[it] = *reinterpret_cast<const float4*>(Xg + (size_t)row * PT + 4 * m);
    }

    // ---- LDS writes: W linear copy (already bf16+swizzled), X cvt ----
    #pragma unroll
    for (int it = 0; it < 8; ++it)
        *reinterpret_cast<uint4*>(&Wlds[t * 8 + it * 2048]) = wr[it];
    #pragma unroll
    for (int it = 0; it < 8; ++it) {
        const int f_i = it * 256 + t;
        const int row = f_i >> 4, m = f_i & 15;
        ushort4 h;
        h.x = f2bf(xr[it].x); h.y = f2bf(xr[it].y);
        h.z = f2bf(xr[it].z); h.w = f2bf(xr[it].w);
        *reinterpret_cast<ushort4*>(&Xlds[row * XLD + 4 * m]) = h;
    }
    __syncthreads();

    // ---- compute: wave wv owns px [wv*16, +16), all 128 output rows ----
    const int lane = t & 63;
    const int wv   = t >> 6;
    const int r    = lane & 15;   // frag row (A: m) / col (B,D: pixel)
    const int q    = lane >> 4;   // k sub-block (A,B) / row block (D)
    const int px   = wv * 16 + r;

    f32x4 acc[8];
    #pragma unroll
    for (int mi = 0; mi < 8; ++mi) acc[mi] = (f32x4){0.f, 0.f, 0.f, 0.f};

    #pragma unroll
    for (int ks = 0; ks < 4; ++ks) {          // K = 128 in 4 MFMA K-steps
        const unsigned short* col = &Xlds[(ks * 32 + q * 8) * XLD + px];
        short tmp[8];
        #pragma unroll
        for (int j = 0; j < 8; ++j) tmp[j] = (short)col[j * XLD];
        const bf16x8 b = (bf16x8){tmp[0], tmp[1], tmp[2], tmp[3],
                                  tmp[4], tmp[5], tmp[6], tmp[7]};
        #pragma unroll
        for (int mi = 0; mi < 8; ++mi) {
            const int mrow = mi * 16 + r;
            const int idx = (mrow * GC + ks * 32 + q * 8) ^ ((mrow & 7) << 3);
            const bf16x8 a = *reinterpret_cast<const bf16x8*>(&Wlds[idx]);
            acc[mi] = __builtin_amdgcn_mfma_f32_16x16x32_bf16(a, b, acc[mi], 0, 0, 0);
        }
    }

    // ---- stores ----
    float* yp = y + (size_t)(g * GC) * PT + p0 + px;
    #pragma unroll
    for (int mi = 0; mi < 8; ++mi) {
        #pragma unroll
        for (int rr = 0; rr < 4; ++rr) {
            yp[(size_t)(mi * 16 + q * 4 + rr) * PT] = acc[mi][rr];
        }
    }
}

extern "C" void kernel_launch(void* const* d_in, const int* in_sizes, int n_in,
                              void* d_out, int out_size, void* d_ws, size_t ws_size,
                              hipStream_t stream) {
    const float* x = (const float*)d_in[0];   // [1, 1024, 256, 256] fp32
    const float* w = (const float*)d_in[1];   // [1024, 1024] fp32
    // d_in[2] = mask: known block-diagonal pattern, not needed.
    float* y = (float*)d_out;                 // [1, 1024, 256, 256] fp32
    unsigned short* wf = (unsigned short*)d_ws;  // 256 KB bf16 W (pre-swizzled)

    wprep_kernel<<<dim3(64), dim3(256), 0, stream>>>(w, wf);
    dim3 grid(PT / BN, 8);   // 1024 pixel tiles x 8 groups = 8192 blocks
    sparse_group_conv_kernel<<<grid, dim3(256), 0, stream>>>(x, wf, y);
}